// Round 7
// baseline (175.634 us; speedup 1.0000x reference)
//
#include <hip/hip_runtime.h>
#include <math.h>

#define R_ROUTES 1152
#define N_CAPS 10
#define C_IN 8
#define D_DIM 16
#define B_BATCH 128
#define JD 160                      // N_CAPS * D_DIM
#define KK 9216                     // R_ROUTES * C_IN (GEMM K)
#define JG 10                       // jd groups of 16 (one cap each)
#define BS 8                        // batch splits of 16
#define NW 8                        // waves per full-K block (512 threads)
#define KW 1152                     // k per wave (KK / NW) = 144 routes
#define NST 36                      // K-steps of 32 per wave

typedef __attribute__((ext_vector_type(8))) short short8;   // 8 bf16 (4 VGPRs)
typedef __attribute__((ext_vector_type(4))) float f32x4;    // MFMA accumulator

__device__ inline unsigned short f2bf(float f) {            // RNE fp32 -> bf16
    unsigned int u = __float_as_uint(f);
    unsigned int r = u + 0x7FFFu + ((u >> 16) & 1u);
    return (unsigned short)(r >> 16);
}
__device__ inline float bf2f(unsigned short h) {
    return __uint_as_float(((unsigned int)h) << 16);
}

// ---------------------------------------------------------------------------
// ws layout (byte offsets):
//   s0   fp32 [128][160]       @ 0        (81920)   plain-stored by k_head
//   s1   fp32 [128][160]       @ 81920    (81920)   plain-stored by k_full<0>
//   b_ij fp32 [1152][10]       @ 163840   (46080; stored by va1, += by va2)
//   ctab fp32 [1152][10]       @ 209920   (46080; softmax(b) written by k_va)
//   xT   bf16 [9216][128]      @ 256000   (2359296; M2 A-operand)
// Lesson log:
//  R7-R12: atomics + occupancy exonerated. R13 (redundant agreement), R14
//    (serial agent-scalar tail), R15 (agent ACQ-spin barrier) all REGRESSED:
//    bad IMPLEMENTATIONS of dispatch-count reduction, each 10-40us poison.
//  R16/R17 (111.6/112.0 == R0's 112.2): THREE different 7-dispatch kernels
//    identical total -> per-dispatch fixed cost ~12-16us dominates; kernel
//    internals neutral. Only lever left: DISPATCH COUNT, cleanly.
//  R18 (this): 7 -> 5 dispatches, no sync tricks, no atomics, no zeroing:
//    - k_full: full-K per block (grid 10x8, 512thr=8 waves; wave ww owns
//      K-slice ww*1152, 36 steps; waves 1-7 -> 7KB LDS; wave 0 reduces and
//      plain-stores its complete 16b x 16jd s-tile). No atomicAdd -> the
//      zero dispatch disappears. iter3 variant squashes in-regs (verified
//      width-16 shfl_xor) and writes out directly -> k_final deleted.
//    - d1 = full-K iter1 (80 blocks) + transpose (144 blocks, 2 tiles each),
//      independent roles fused.
// ---------------------------------------------------------------------------

// Full-K routing GEMM body. Fragment math identical to verified R16/R17
// iter_body (route rr = rbase + st*4 + quad; B[i] = bf16(c*W[rr][jd][i]);
// A from x fp32 hi/lo split). Wave ww covers routes [ww*144, ww*144+144).
template <int FIRST, int FINAL>
__device__ inline void full_body(
    const float* __restrict__ x, const float* __restrict__ W,
    const float* __restrict__ ctab, float* __restrict__ dst,
    f32x4 (*__restrict__ red)[64], int jg, int bs, int t) {
    int jd0 = jg * 16, b0 = bs * 16;
    int ww = t >> 6, l = t & 63, row = l & 15, quad = l >> 4;
    const float* px = x + (size_t)(b0 + row) * KK + ww * KW;
    int rbase = ww * (KW / C_IN);             // 144 routes per wave
    f32x4 acc = {0, 0, 0, 0};
#pragma unroll 4
    for (int st = 0; st < NST; st++) {        // 36 steps of 32 k
        int rr = rbase + st * 4 + quad;       // route of this fragment
        float c0 = FIRST ? 0.1f : ctab[rr * N_CAPS + jg];
        const float4* wp = (const float4*)(W + ((size_t)rr * JD + jd0 + row) * C_IN);
        float4 wa = wp[0], wb = wp[1];
        float wv[8] = {wa.x, wa.y, wa.z, wa.w, wb.x, wb.y, wb.z, wb.w};
        short8 Bh;
#pragma unroll
        for (int i = 0; i < 8; i++) Bh[i] = (short)f2bf(wv[i] * c0);
        float4 x0 = *(const float4*)(px + st * 32 + quad * 8);
        float4 x1 = *(const float4*)(px + st * 32 + quad * 8 + 4);
        float xv[8] = {x0.x, x0.y, x0.z, x0.w, x1.x, x1.y, x1.z, x1.w};
        short8 Ah, Al;
#pragma unroll
        for (int i = 0; i < 8; i++) {
            unsigned short h = f2bf(xv[i]);
            Ah[i] = (short)h;
            Al[i] = (short)f2bf(xv[i] - bf2f(h));
        }
        acc = __builtin_amdgcn_mfma_f32_16x16x32_bf16(Ah, Bh, acc, 0, 0, 0);
        acc = __builtin_amdgcn_mfma_f32_16x16x32_bf16(Al, Bh, acc, 0, 0, 0);
    }
    // cross-wave reduce: waves 1..7 park in LDS, wave 0 sums
    if (ww > 0) red[ww - 1][l] = acc;
    __syncthreads();
    if (ww == 0) {
#pragma unroll
        for (int j = 0; j < NW - 1; j++) {
            f32x4 r = red[j][l];
            acc[0] += r[0]; acc[1] += r[1]; acc[2] += r[2]; acc[3] += r[3];
        }
        // C/D: col = row (jd), row = quad*4+i (b)  [verified layout]
        if (FINAL) {                          // squash in-regs -> out
#pragma unroll
            for (int i = 0; i < 4; i++) {
                float v = acc[i], sq = v * v; // d = row -> width-16 xor reduce
#pragma unroll
                for (int off = 1; off < 16; off <<= 1) sq += __shfl_xor(sq, off, 16);
                float scale = sq / ((1.f + sq) * sqrtf(sq));
                dst[(size_t)(b0 + quad * 4 + i) * JD + jd0 + row] = v * scale;
            }
        } else {                              // plain-store complete s-tile
#pragma unroll
            for (int i = 0; i < 4; i++)
                dst[(size_t)(b0 + quad * 4 + i) * JD + jd0 + row] = acc[i];
        }
    }
}

// d1: blocks 0..79 = full-K iter1 (c=0.1) -> s0; blocks 80..223 = transpose
// x -> xT (2 rc-tiles per 512-thread block).
__global__ __launch_bounds__(512) void k_head(
    const float* __restrict__ x, const float* __restrict__ W,
    unsigned short* __restrict__ xT, float* __restrict__ s0) {
    __shared__ f32x4 red[NW - 1][64];         // 7168 B
    __shared__ float tile[2][32][33];         // 8448 B
    int id = blockIdx.x, t = threadIdx.x;
    if (id < JG * BS) {                       // ---- iter1 role ----
        full_body<1, 0>(x, W, nullptr, s0, red, id % JG, id / JG, t);
        return;
    }
    // ---- transpose role: 2 tiles per block ----
    int sub = t >> 8, tt = t & 255;
    int bx = (id - JG * BS) * 2 + sub;        // rc tile 0..287
    int tx = tt & 31, ty = tt >> 5;
    for (int by = 0; by < 4; by++) {
        if (by) __syncthreads();
#pragma unroll
        for (int i = 0; i < 4; i++) {
            int row = ty + i * 8;             // b_local
            tile[sub][row][tx] = x[(size_t)(by * 32 + row) * KK + bx * 32 + tx];
        }
        __syncthreads();
#pragma unroll
        for (int i = 0; i < 4; i++) {
            int row = ty + i * 8;             // rc_local
            xT[(size_t)(bx * 32 + row) * B_BATCH + by * 32 + tx] = f2bf(tile[sub][tx][row]);
        }
    }
}

// Standalone full-K iteration (iter2: FINAL=0 -> s1; iter3: FINAL=1 -> out).
template <int FINAL>
__global__ __launch_bounds__(512) void k_full(
    const float* __restrict__ x, const float* __restrict__ W,
    const float* __restrict__ ctab, float* __restrict__ dst) {
    __shared__ f32x4 red[NW - 1][64];
    full_body<0, FINAL>(x, W, ctab, dst, red, blockIdx.x, blockIdx.y, threadIdx.x);
}

// Agreement + softmax (verified R16/R17): squash(s_prev)->vb, M2 via MFMA
// with in-register W contract, b_new for block's 4 routes, softmax -> ctab.
// ACCUM=0 (va1): b_ij = upd (store).  ACCUM=1 (va2): b_ij + upd.
template <int ACCUM>
__global__ __launch_bounds__(256) void k_va(
    const unsigned short* __restrict__ xT, const float* __restrict__ s_prev,
    const float* __restrict__ W, float* __restrict__ b_ij,
    float* __restrict__ ctab) {
    __shared__ unsigned short vb[JD][136];    // [jd][b], +8 pad (43520 B)
    __shared__ float bnew[4][N_CAPS];
    int t = threadIdx.x;
    int r0 = blockIdx.x * 4, rc0 = blockIdx.x * 32;

    // --- squash(s_prev) -> vb --------------------------------------------
#pragma unroll
    for (int q = 0; q < 5; q++) {
        int pi = t * 5 + q;                   // (b, j) pair, 1280 total
        int b = pi / N_CAPS, j = pi % N_CAPS;
        const float4* sp4 = (const float4*)(s_prev + (size_t)b * JD + j * D_DIM);
        float4 a0 = sp4[0], a1 = sp4[1], a2 = sp4[2], a3 = sp4[3];
        float sv[D_DIM] = {a0.x,a0.y,a0.z,a0.w, a1.x,a1.y,a1.z,a1.w,
                           a2.x,a2.y,a2.z,a2.w, a3.x,a3.y,a3.z,a3.w};
        float sqn = 0.f;
#pragma unroll
        for (int d = 0; d < D_DIM; d++) sqn = fmaf(sv[d], sv[d], sqn);
        float scale = sqn / ((1.f + sqn) * sqrtf(sqn));
#pragma unroll
        for (int d = 0; d < D_DIM; d++)
            vb[j * D_DIM + d][b] = f2bf(sv[d] * scale);
    }
    __syncthreads();

    int w = t >> 6, l = t & 63, row = l & 15, quad = l >> 4;
    int rhalf = l >> 5, cbase = (quad & 1) * 4;

    // --- M2 tiles + in-register W contract, 5 tiles/wave -----------------
#pragma unroll
    for (int jt = 0; jt < 5; jt++) {          // u = jt*4 + w
        int u = jt * 4 + w;
        int mt = u / 10, nt = u % 10;
        const short8* pa = (const short8*)(xT + (size_t)(rc0 + mt * 16 + row) * B_BATCH);
        f32x4 acc = {0, 0, 0, 0};
#pragma unroll
        for (int st = 0; st < 4; st++)        // K = 128 = 4 steps of 32
            acc = __builtin_amdgcn_mfma_f32_16x16x32_bf16(
                pa[st * 4 + quad],
                *(const short8*)&vb[nt * 16 + row][st * 32 + quad * 8],
                acc, 0, 0, 0);
        int r = r0 + 2 * mt + rhalf;
        const float* wp = W + ((size_t)r * JD + nt * 16 + row) * C_IN + cbase;
        float4 w4 = *(const float4*)wp;
        float part = acc[0]*w4.x + acc[1]*w4.y + acc[2]*w4.z + acc[3]*w4.w;
#pragma unroll
        for (int off = 1; off < 32; off <<= 1) part += __shfl_xor(part, off, 32);
        if ((l & 31) == 0) bnew[2 * mt + rhalf][nt] = part * (1.f / (float)B_BATCH);
    }
    __syncthreads();

    // --- softmax for this block's 4 routes -> ctab (and b_ij chain) ------
    if (t < 4) {
        float bj[N_CAPS], m = -1e30f;
#pragma unroll
        for (int j = 0; j < N_CAPS; j++) {
            float base = ACCUM ? b_ij[(r0 + t) * N_CAPS + j] : 0.f;
            bj[j] = base + bnew[t][j];
            m = fmaxf(m, bj[j]);
        }
        if (!ACCUM) {
#pragma unroll
            for (int j = 0; j < N_CAPS; j++) b_ij[(r0 + t) * N_CAPS + j] = bj[j];
        }
        float sum = 0.f;
#pragma unroll
        for (int j = 0; j < N_CAPS; j++) { bj[j] = expf(bj[j] - m); sum += bj[j]; }
        float inv = 1.f / sum;
#pragma unroll
        for (int j = 0; j < N_CAPS; j++) ctab[(r0 + t) * N_CAPS + j] = bj[j] * inv;
    }
}

extern "C" void kernel_launch(void* const* d_in, const int* in_sizes, int n_in,
                              void* d_out, int out_size, void* d_ws, size_t ws_size,
                              hipStream_t stream) {
    const float* x = (const float*)d_in[0];   // [128,1152,8]
    const float* W = (const float*)d_in[1];   // [1,1152,10,16,8]
    float* out = (float*)d_out;               // [128,10,16,1]
    char* ws = (char*)d_ws;

    float*          s0   = (float*)(ws + 0);
    float*          s1   = (float*)(ws + 81920);
    float*          b_ij = (float*)(ws + 163840);
    float*          ctab = (float*)(ws + 209920);
    unsigned short* xT   = (unsigned short*)(ws + 256000);

    // d1: full-K iter1 (c=0.1) -> s0  +  transpose x -> xT
    k_head<<<JG * BS + 144, 512, 0, stream>>>(x, W, xT, s0);

    // d2: va1 -> b_ij (store), ctab
    k_va<0><<<288, 256, 0, stream>>>(xT, s0, W, b_ij, ctab);

    // d3: full-K iter2 -> s1
    k_full<0><<<dim3(JG, BS), 512, 0, stream>>>(x, W, ctab, s1);

    // d4: va2 -> ctab (b_ij + upd2)
    k_va<1><<<288, 256, 0, stream>>>(xT, s1, W, b_ij, ctab);

    // d5: full-K iter3 + in-block squash -> out
    k_full<1><<<dim3(JG, BS), 512, 0, stream>>>(x, W, ctab, out);
}

// Round 8
// 151.745 us; speedup vs baseline: 1.1574x; 1.1574x over previous
//
#include <hip/hip_runtime.h>
#include <math.h>

#define R_ROUTES 1152
#define N_CAPS 10
#define C_IN 8
#define D_DIM 16
#define B_BATCH 128
#define JD 160                      // N_CAPS * D_DIM
#define KK 9216                     // R_ROUTES * C_IN (GEMM K)
#define JG 10                       // jd groups of 16 (one cap each)
#define BS 8                        // batch splits of 16
#define NW 16                       // waves per full-K block (1024 threads)
#define KW 576                      // k per wave (KK / NW) = 72 routes
#define NST 18                      // K-steps of 32 per wave
#define RPW 72                      // routes per wave

typedef __attribute__((ext_vector_type(8))) short short8;   // 8 bf16 (4 VGPRs)
typedef __attribute__((ext_vector_type(4))) float f32x4;    // MFMA accumulator

__device__ inline unsigned short f2bf(float f) {            // RNE fp32 -> bf16
    unsigned int u = __float_as_uint(f);
    unsigned int r = u + 0x7FFFu + ((u >> 16) & 1u);
    return (unsigned short)(r >> 16);
}
__device__ inline float bf2f(unsigned short h) {
    return __uint_as_float(((unsigned int)h) << 16);
}

// ---------------------------------------------------------------------------
// ws layout (byte offsets):
//   s0   fp32 [128][160]       @ 0        (81920)   plain-stored by k_head
//   s1   fp32 [128][160]       @ 81920    (81920)   plain-stored by k_full<0>
//   b_ij fp32 [1152][10]       @ 163840   (46080; stored by va1, += by va2)
//   ctab fp32 [1152][10]       @ 209920   (46080; softmax(b) by k_va)
//   xT   bf16 [9216][128]      @ 256000   (2359296; M2 A-operand)
//   xh   bf16 [128][9216]      @ 2615296  (2359296; A hi, written by d1)
//   xl   bf16 [128][9216]      @ 4974592  (2359296; A lo)
// Lesson log:
//  R13/R14/R15: redundant agreement / serial agent tails / spin barriers all
//    10-40us poison. R16/R17 (112us == R0): three 7-dispatch kernels, same
//    total -> gaps ~5-6us, va ~10-13us, iter ~8-13us; iters are per-wave
//    critical-path bound (R12 occupancy-doubling neutral, R9 MFMA-drop
//    neutral).
//  R18 REGRESSED (176us) but PASSED: 5-dispatch full-K chain correct; k_full
//    at 8 waves/36 serial steps/2.5 waves-per-CU = 40us each. Structure ok,
//    depth wrong.
//  R19 (this): same 5-dispatch chain, k_full fixed on both axes:
//    - 1024-thread blocks (16 waves): serial chain 36 -> 18 steps, 4
//      waves/SIMD latency hiding.
//    - xh/xl precomputed in d1's transpose role (R0-verified bit patterns):
//      iter2/3 load A as short8 (half bytes, zero A-conversion VALU).
//    No atomics, no zeroing, no counters, no cross-block sync.
// ---------------------------------------------------------------------------

// Full-K routing GEMM body (R18-verified math, NW=16 depth).
// Wave ww covers routes [ww*72, ww*72+72) = k slice [ww*576, +576).
// FIRST: c=0.1, A from fp32 x (xh/xl not ready). Else: A from xh/xl bf16.
template <int FIRST, int FINAL>
__device__ inline void full_body(
    const float* __restrict__ x, const unsigned short* __restrict__ xh,
    const unsigned short* __restrict__ xl, const float* __restrict__ W,
    const float* __restrict__ ctab, float* __restrict__ dst,
    f32x4 (*__restrict__ red)[64], int jg, int bs, int t) {
    int jd0 = jg * 16, b0 = bs * 16;
    int ww = t >> 6, l = t & 63, row = l & 15, quad = l >> 4;
    int rbase = ww * RPW;
    f32x4 acc = {0, 0, 0, 0};
#pragma unroll 3
    for (int st = 0; st < NST; st++) {        // 18 steps of 32 k
        int rr = rbase + st * 4 + quad;       // route of this fragment
        float c0 = FIRST ? 0.1f : ctab[rr * N_CAPS + jg];
        const float4* wp = (const float4*)(W + ((size_t)rr * JD + jd0 + row) * C_IN);
        float4 wa = wp[0], wb = wp[1];
        float wv[8] = {wa.x, wa.y, wa.z, wa.w, wb.x, wb.y, wb.z, wb.w};
        short8 Bh;
#pragma unroll
        for (int i = 0; i < 8; i++) Bh[i] = (short)f2bf(wv[i] * c0);
        short8 Ah, Al;
        if (FIRST) {
            const float* px = x + (size_t)(b0 + row) * KK + ww * KW;
            float4 x0 = *(const float4*)(px + st * 32 + quad * 8);
            float4 x1 = *(const float4*)(px + st * 32 + quad * 8 + 4);
            float xv[8] = {x0.x, x0.y, x0.z, x0.w, x1.x, x1.y, x1.z, x1.w};
#pragma unroll
            for (int i = 0; i < 8; i++) {
                unsigned short h = f2bf(xv[i]);
                Ah[i] = (short)h;
                Al[i] = (short)f2bf(xv[i] - bf2f(h));
            }
        } else {
            const short8* ph = (const short8*)(xh + (size_t)(b0 + row) * KK + ww * KW);
            const short8* pl = (const short8*)(xl + (size_t)(b0 + row) * KK + ww * KW);
            Ah = ph[st * 4 + quad];
            Al = pl[st * 4 + quad];
        }
        acc = __builtin_amdgcn_mfma_f32_16x16x32_bf16(Ah, Bh, acc, 0, 0, 0);
        acc = __builtin_amdgcn_mfma_f32_16x16x32_bf16(Al, Bh, acc, 0, 0, 0);
    }
    // cross-wave reduce: waves 1..15 park in LDS, wave 0 sums (R18-verified)
    if (ww > 0) red[ww - 1][l] = acc;
    __syncthreads();
    if (ww == 0) {
#pragma unroll
        for (int j = 0; j < NW - 1; j++) {
            f32x4 r = red[j][l];
            acc[0] += r[0]; acc[1] += r[1]; acc[2] += r[2]; acc[3] += r[3];
        }
        // C/D: col = row (jd), row = quad*4+i (b)  [verified layout]
        if (FINAL) {                          // squash in-regs -> out (R18-verified)
#pragma unroll
            for (int i = 0; i < 4; i++) {
                float v = acc[i], sq = v * v; // d = row -> width-16 xor reduce
#pragma unroll
                for (int off = 1; off < 16; off <<= 1) sq += __shfl_xor(sq, off, 16);
                float scale = sq / ((1.f + sq) * sqrtf(sq));
                dst[(size_t)(b0 + quad * 4 + i) * JD + jd0 + row] = v * scale;
            }
        } else {                              // plain-store complete s-tile
#pragma unroll
            for (int i = 0; i < 4; i++)
                dst[(size_t)(b0 + quad * 4 + i) * JD + jd0 + row] = acc[i];
        }
    }
}

// d1: blocks 0..79 = full-K iter1 (c=0.1) -> s0;
//     blocks 80..151 = transpose x -> xT + produce xh/xl (4 rc-tiles each).
__global__ __launch_bounds__(1024) void k_head(
    const float* __restrict__ x, const float* __restrict__ W,
    unsigned short* __restrict__ xT, unsigned short* __restrict__ xh,
    unsigned short* __restrict__ xl, float* __restrict__ s0) {
    __shared__ f32x4 red[NW - 1][64];         // 15360 B
    __shared__ float tile[4][32][33];         // 16896 B
    int id = blockIdx.x, t = threadIdx.x;
    if (id < JG * BS) {                       // ---- iter1 role ----
        full_body<1, 0>(x, nullptr, nullptr, W, nullptr, s0, red,
                        id % JG, id / JG, t);
        return;
    }
    // ---- transpose + xh/xl role: 4 rc-tiles per block ----
    int sub = t >> 8, tt = t & 255;
    int bx = (id - JG * BS) * 4 + sub;        // rc tile 0..287
    int tx = tt & 31, ty = tt >> 5;
    for (int by = 0; by < 4; by++) {
        if (by) __syncthreads();
#pragma unroll
        for (int i = 0; i < 4; i++) {
            int row = ty + i * 8;             // b_local
            size_t idx = (size_t)(by * 32 + row) * KK + bx * 32 + tx;
            float v = x[idx];
            tile[sub][row][tx] = v;
            unsigned short hi = f2bf(v);
            xh[idx] = hi;
            xl[idx] = f2bf(v - bf2f(hi));
        }
        __syncthreads();
#pragma unroll
        for (int i = 0; i < 4; i++) {
            int row = ty + i * 8;             // rc_local
            xT[(size_t)(bx * 32 + row) * B_BATCH + by * 32 + tx] = f2bf(tile[sub][tx][row]);
        }
    }
}

// Standalone full-K iteration (iter2: FINAL=0 -> s1; iter3: FINAL=1 -> out).
template <int FINAL>
__global__ __launch_bounds__(1024) void k_full(
    const unsigned short* __restrict__ xh, const unsigned short* __restrict__ xl,
    const float* __restrict__ W, const float* __restrict__ ctab,
    float* __restrict__ dst) {
    __shared__ f32x4 red[NW - 1][64];
    full_body<0, FINAL>(nullptr, xh, xl, W, ctab, dst, red,
                        blockIdx.x, blockIdx.y, threadIdx.x);
}

// Agreement + softmax (verified R16/R17): squash(s_prev)->vb, M2 via MFMA
// with in-register W contract, b_new for block's 4 routes, softmax -> ctab.
// ACCUM=0 (va1): b_ij = upd (store).  ACCUM=1 (va2): b_ij + upd.
template <int ACCUM>
__global__ __launch_bounds__(256) void k_va(
    const unsigned short* __restrict__ xT, const float* __restrict__ s_prev,
    const float* __restrict__ W, float* __restrict__ b_ij,
    float* __restrict__ ctab) {
    __shared__ unsigned short vb[JD][136];    // [jd][b], +8 pad (43520 B)
    __shared__ float bnew[4][N_CAPS];
    int t = threadIdx.x;
    int r0 = blockIdx.x * 4, rc0 = blockIdx.x * 32;

    // --- squash(s_prev) -> vb --------------------------------------------
#pragma unroll
    for (int q = 0; q < 5; q++) {
        int pi = t * 5 + q;                   // (b, j) pair, 1280 total
        int b = pi / N_CAPS, j = pi % N_CAPS;
        const float4* sp4 = (const float4*)(s_prev + (size_t)b * JD + j * D_DIM);
        float4 a0 = sp4[0], a1 = sp4[1], a2 = sp4[2], a3 = sp4[3];
        float sv[D_DIM] = {a0.x,a0.y,a0.z,a0.w, a1.x,a1.y,a1.z,a1.w,
                           a2.x,a2.y,a2.z,a2.w, a3.x,a3.y,a3.z,a3.w};
        float sqn = 0.f;
#pragma unroll
        for (int d = 0; d < D_DIM; d++) sqn = fmaf(sv[d], sv[d], sqn);
        float scale = sqn / ((1.f + sqn) * sqrtf(sqn));
#pragma unroll
        for (int d = 0; d < D_DIM; d++)
            vb[j * D_DIM + d][b] = f2bf(sv[d] * scale);
    }
    __syncthreads();

    int w = t >> 6, l = t & 63, row = l & 15, quad = l >> 4;
    int rhalf = l >> 5, cbase = (quad & 1) * 4;

    // --- M2 tiles + in-register W contract, 5 tiles/wave -----------------
#pragma unroll
    for (int jt = 0; jt < 5; jt++) {          // u = jt*4 + w
        int u = jt * 4 + w;
        int mt = u / 10, nt = u % 10;
        const short8* pa = (const short8*)(xT + (size_t)(rc0 + mt * 16 + row) * B_BATCH);
        f32x4 acc = {0, 0, 0, 0};
#pragma unroll
        for (int st = 0; st < 4; st++)        // K = 128 = 4 steps of 32
            acc = __builtin_amdgcn_mfma_f32_16x16x32_bf16(
                pa[st * 4 + quad],
                *(const short8*)&vb[nt * 16 + row][st * 32 + quad * 8],
                acc, 0, 0, 0);
        int r = r0 + 2 * mt + rhalf;
        const float* wp = W + ((size_t)r * JD + nt * 16 + row) * C_IN + cbase;
        float4 w4 = *(const float4*)wp;
        float part = acc[0]*w4.x + acc[1]*w4.y + acc[2]*w4.z + acc[3]*w4.w;
#pragma unroll
        for (int off = 1; off < 32; off <<= 1) part += __shfl_xor(part, off, 32);
        if ((l & 31) == 0) bnew[2 * mt + rhalf][nt] = part * (1.f / (float)B_BATCH);
    }
    __syncthreads();

    // --- softmax for this block's 4 routes -> ctab (and b_ij chain) ------
    if (t < 4) {
        float bj[N_CAPS], m = -1e30f;
#pragma unroll
        for (int j = 0; j < N_CAPS; j++) {
            float base = ACCUM ? b_ij[(r0 + t) * N_CAPS + j] : 0.f;
            bj[j] = base + bnew[t][j];
            m = fmaxf(m, bj[j]);
        }
        if (!ACCUM) {
#pragma unroll
            for (int j = 0; j < N_CAPS; j++) b_ij[(r0 + t) * N_CAPS + j] = bj[j];
        }
        float sum = 0.f;
#pragma unroll
        for (int j = 0; j < N_CAPS; j++) { bj[j] = expf(bj[j] - m); sum += bj[j]; }
        float inv = 1.f / sum;
#pragma unroll
        for (int j = 0; j < N_CAPS; j++) ctab[(r0 + t) * N_CAPS + j] = bj[j] * inv;
    }
}

extern "C" void kernel_launch(void* const* d_in, const int* in_sizes, int n_in,
                              void* d_out, int out_size, void* d_ws, size_t ws_size,
                              hipStream_t stream) {
    const float* x = (const float*)d_in[0];   // [128,1152,8]
    const float* W = (const float*)d_in[1];   // [1,1152,10,16,8]
    float* out = (float*)d_out;               // [128,10,16,1]
    char* ws = (char*)d_ws;

    float*          s0   = (float*)(ws + 0);
    float*          s1   = (float*)(ws + 81920);
    float*          b_ij = (float*)(ws + 163840);
    float*          ctab = (float*)(ws + 209920);
    unsigned short* xT   = (unsigned short*)(ws + 256000);
    unsigned short* xh   = (unsigned short*)(ws + 2615296);
    unsigned short* xl   = (unsigned short*)(ws + 4974592);

    // d1: full-K iter1 (c=0.1) -> s0  +  transpose x -> xT, produce xh/xl
    k_head<<<JG * BS + 72, 1024, 0, stream>>>(x, W, xT, xh, xl, s0);

    // d2: va1 -> b_ij (store), ctab
    k_va<0><<<288, 256, 0, stream>>>(xT, s0, W, b_ij, ctab);

    // d3: full-K iter2 -> s1
    k_full<0><<<dim3(JG, BS), 1024, 0, stream>>>(xh, xl, W, ctab, s1);

    // d4: va2 -> ctab (b_ij + upd2)
    k_va<1><<<288, 256, 0, stream>>>(xT, s1, W, b_ij, ctab);

    // d5: full-K iter3 + in-block squash -> out
    k_full<1><<<dim3(JG, BS), 1024, 0, stream>>>(xh, xl, W, ctab, out);
}

// Round 9
// 115.211 us; speedup vs baseline: 1.5244x; 1.3171x over previous
//
#include <hip/hip_runtime.h>
#include <math.h>

#define R_ROUTES 1152
#define N_CAPS 10
#define C_IN 8
#define D_DIM 16
#define B_BATCH 128
#define JD 160                      // N_CAPS * D_DIM
#define KK 9216                     // R_ROUTES * C_IN (GEMM K)
#define KSPLIT 48                   // 24 routes = 192 k per split
#define RS 24                       // routes per k-split
#define NG 5                        // jd groups of 32
#define BH 2                        // batch halves

typedef __attribute__((ext_vector_type(8))) short short8;   // 8 bf16 (4 VGPRs)
typedef __attribute__((ext_vector_type(4))) float f32x4;    // MFMA accumulator

__device__ inline unsigned short f2bf(float f) {            // RNE fp32 -> bf16
    unsigned int u = __float_as_uint(f);
    unsigned int r = u + 0x7FFFu + ((u >> 16) & 1u);
    return (unsigned short)(r >> 16);
}
__device__ inline float bf2f(unsigned short h) {
    return __uint_as_float(((unsigned int)h) << 16);
}

// ---------------------------------------------------------------------------
// ws layout (byte offsets):
//   s0   fp32 [128][160]       @ 0        (81920)
//   s1   fp32 [128][160]       @ 81920    (81920)
//   s2   fp32 [128][160]       @ 163840   (81920)  [s0..s2 zeroed in d1]
//   b_ij fp32 [1152][10]       @ 245760   (46080; stored by va1, += by va2)
//   ctab fp32 [1152][10]       @ 291840   (46080; softmax(b) by k_va)
//   xT   bf16 [9216][128]      @ 337920   (2359296; M2 A-operand)
// Lesson log:
//  R13/R14/R15: redundant agreement / serial agent tails / spin barriers =
//    10-40us poison each. R16/R17 (111.6/112.0 == R0 112.2): three different
//    7-dispatch kernels tie; internals neutral. R18/R19 (176/152): 5-dispatch
//    full-K slow at ANY depth (80 blocks only).
//  NEW MODEL (from R13/R15 PMC): k-kernels fetch 6.8MB HBM at 200-270 GB/s
//    (4% of peak; harness fills hit 6500). The 268MB re-poison evicts L3
//    before each replay; every GEMM dispatch then TRICKLES W(5.9MB)+x(4.7MB)
//    through its dependency-ordered loads with tiny MLP (~25us latency-bound
//    fetch). Explains: 3-way tie at 112 (same cold-fetch), R12 occupancy
//    neutral (MLP-limited not wave-limited), full-K 3-4x slower (80 CUs
//    issuing vs 240).
//  R20 (this): ISOLATED change vs R17 baseline: d1 gains a W-warm role
//    (96 blocks x 256thr x 15 independent float4 = exactly W's 1,474,560
//    floats, asm keep-alive) -> W streams to L3 at fill-like MLP; transpose
//    role already streams all of x. d2-d7 BIT-IDENTICAL to verified kernels
//    (iter3 back to atomic; s2 zeroed in d1). Predict dur 85-100; if
//    neutral, trickle theory is dead and plateau = launch fixed cost.
// ---------------------------------------------------------------------------

// d1: blocks 0..287 transpose x -> xT; 288..347 zero s0+s1+s2;
//     348..443 warm W into L3 (read-only, kept alive).
__global__ __launch_bounds__(256) void k_prep0(
    const float* __restrict__ x, const float* __restrict__ W,
    unsigned short* __restrict__ xT, f32x4* __restrict__ zbase) {
    __shared__ float tile[32][33];
    int id = blockIdx.x, t = threadIdx.x;
    if (id < 288) {                           // ---- transpose role ----
        int bx = id;                          // rc tile 0..287
        int tx = t & 31, ty = t >> 5;
        for (int by = 0; by < 4; by++) {
            if (by) __syncthreads();
#pragma unroll
            for (int i = 0; i < 4; i++) {
                int row = ty + i * 8;         // b_local
                tile[row][tx] = x[(size_t)(by * 32 + row) * KK + bx * 32 + tx];
            }
            __syncthreads();
#pragma unroll
            for (int i = 0; i < 4; i++) {
                int row = ty + i * 8;         // rc_local
                xT[(size_t)(bx * 32 + row) * B_BATCH + by * 32 + tx] = f2bf(tile[tx][row]);
            }
        }
        return;
    }
    if (id < 348) {                           // ---- zero role: s0..s2 ----
        int idx = (id - 288) * 256 + t;       // 60*256 = 15360 f32x4 = 245760 B
        zbase[idx] = (f32x4){0.f, 0.f, 0.f, 0.f};
        return;
    }
    // ---- W-warm role: stream W (1,474,560 floats = 368,640 f32x4) -------
    // 96 blocks x 256 thr x 15 independent float4 loads; asm keeps them live
    // (rule: ablation-via-skip DCEs upstream ops). Pure L3 side-effect.
    int wb = id - 348;                        // 0..95
    const f32x4* wp = (const f32x4*)W;
    size_t base = (size_t)wb * 3840 + t;
#pragma unroll
    for (int i = 0; i < 15; i++) {
        f32x4 v = wp[base + i * 256];
        asm volatile("" :: "v"(v[0]), "v"(v[1]), "v"(v[2]), "v"(v[3]));
    }
}

// One routing iteration's weighted-sum GEMM (R16/R17-verified, atomic path).
// No LDS, no barriers. B-fragments built from global W in regs (fragment
// route rl = st*4+quad), A from x fp32 hi/lo split. atomicAdd into s.
template <int FIRST>
__global__ __launch_bounds__(256) void k_iter(
    const float* __restrict__ x, const float* __restrict__ W,
    const float* __restrict__ ctab, float* __restrict__ s) {
    int t = threadIdx.x;
    int ks = blockIdx.x, ng = blockIdx.y, bh = blockIdx.z;
    int r0 = ks * RS, jd0 = ng * 32, b_base = bh * 64;
    int w = t >> 6, l = t & 63, row = l & 15, quad = l >> 4;
    const float* px = x + (size_t)(b_base + w * 16 + row) * KK + ks * 192;
    f32x4 acc0 = {0,0,0,0}, acc1 = {0,0,0,0};
#pragma unroll
    for (int st = 0; st < 6; st++) {          // K = 192 = 6 steps of 32
        int rr = r0 + st * 4 + quad;          // route of this fragment
        float c0 = FIRST ? 0.1f : ctab[rr * N_CAPS + (jd0 >> 4)];
        float c1 = FIRST ? 0.1f : ctab[rr * N_CAPS + (jd0 >> 4) + 1];
        const float4* wp0 = (const float4*)(W + ((size_t)rr * JD + jd0 + row) * C_IN);
        const float4* wp1 = (const float4*)(W + ((size_t)rr * JD + jd0 + 16 + row) * C_IN);
        float4 wa = wp0[0], wb = wp0[1], wc = wp1[0], wd = wp1[1];
        float wv0[8] = {wa.x,wa.y,wa.z,wa.w, wb.x,wb.y,wb.z,wb.w};
        float wv1[8] = {wc.x,wc.y,wc.z,wc.w, wd.x,wd.y,wd.z,wd.w};
        short8 Bh0, Bh1;
#pragma unroll
        for (int i = 0; i < 8; i++) {
            Bh0[i] = (short)f2bf(wv0[i] * c0);
            Bh1[i] = (short)f2bf(wv1[i] * c1);
        }
        float4 x0 = *(const float4*)(px + st * 32 + quad * 8);
        float4 x1 = *(const float4*)(px + st * 32 + quad * 8 + 4);
        float xv[8] = {x0.x,x0.y,x0.z,x0.w, x1.x,x1.y,x1.z,x1.w};
        short8 Ah, Al;
#pragma unroll
        for (int i = 0; i < 8; i++) {
            unsigned short h = f2bf(xv[i]);
            Ah[i] = (short)h;
            Al[i] = (short)f2bf(xv[i] - bf2f(h));
        }
        acc0 = __builtin_amdgcn_mfma_f32_16x16x32_bf16(Ah, Bh0, acc0, 0, 0, 0);
        acc0 = __builtin_amdgcn_mfma_f32_16x16x32_bf16(Al, Bh0, acc0, 0, 0, 0);
        acc1 = __builtin_amdgcn_mfma_f32_16x16x32_bf16(Ah, Bh1, acc1, 0, 0, 0);
        acc1 = __builtin_amdgcn_mfma_f32_16x16x32_bf16(Al, Bh1, acc1, 0, 0, 0);
    }
#pragma unroll
    for (int i = 0; i < 4; i++) {             // C/D: col=lane&15 (jd), row=quad*4+i (b)
        int b0 = b_base + w * 16 + quad * 4 + i;
        atomicAdd(&s[(size_t)b0 * JD + jd0 + row],      acc0[i]);
        atomicAdd(&s[(size_t)b0 * JD + jd0 + 16 + row], acc1[i]);
    }
}

// Agreement + softmax (verified R16/R17): squash(s_prev)->vb, M2 via MFMA
// with in-register W contract, b_new for block's 4 routes, softmax -> ctab.
// ACCUM=0 (va1): b_ij = upd (store).  ACCUM=1 (va2): b_ij + upd.
template <int ACCUM>
__global__ __launch_bounds__(256) void k_va(
    const unsigned short* __restrict__ xT, const float* __restrict__ s_prev,
    const float* __restrict__ W, float* __restrict__ b_ij,
    float* __restrict__ ctab) {
    __shared__ unsigned short vb[JD][136];    // [jd][b], +8 pad (43520 B)
    __shared__ float bnew[4][N_CAPS];
    int t = threadIdx.x;
    int r0 = blockIdx.x * 4, rc0 = blockIdx.x * 32;

    // --- squash(s_prev) -> vb --------------------------------------------
#pragma unroll
    for (int q = 0; q < 5; q++) {
        int pi = t * 5 + q;                   // (b, j) pair, 1280 total
        int b = pi / N_CAPS, j = pi % N_CAPS;
        const float4* sp4 = (const float4*)(s_prev + (size_t)b * JD + j * D_DIM);
        float4 a0 = sp4[0], a1 = sp4[1], a2 = sp4[2], a3 = sp4[3];
        float sv[D_DIM] = {a0.x,a0.y,a0.z,a0.w, a1.x,a1.y,a1.z,a1.w,
                           a2.x,a2.y,a2.z,a2.w, a3.x,a3.y,a3.z,a3.w};
        float sqn = 0.f;
#pragma unroll
        for (int d = 0; d < D_DIM; d++) sqn = fmaf(sv[d], sv[d], sqn);
        float scale = sqn / ((1.f + sqn) * sqrtf(sqn));
#pragma unroll
        for (int d = 0; d < D_DIM; d++)
            vb[j * D_DIM + d][b] = f2bf(sv[d] * scale);
    }
    __syncthreads();

    int w = t >> 6, l = t & 63, row = l & 15, quad = l >> 4;
    int rhalf = l >> 5, cbase = (quad & 1) * 4;

    // --- M2 tiles + in-register W contract, 5 tiles/wave -----------------
#pragma unroll
    for (int jt = 0; jt < 5; jt++) {          // u = jt*4 + w
        int u = jt * 4 + w;
        int mt = u / 10, nt = u % 10;
        const short8* pa = (const short8*)(xT + (size_t)(rc0 + mt * 16 + row) * B_BATCH);
        f32x4 acc = {0, 0, 0, 0};
#pragma unroll
        for (int st = 0; st < 4; st++)        // K = 128 = 4 steps of 32
            acc = __builtin_amdgcn_mfma_f32_16x16x32_bf16(
                pa[st * 4 + quad],
                *(const short8*)&vb[nt * 16 + row][st * 32 + quad * 8],
                acc, 0, 0, 0);
        int r = r0 + 2 * mt + rhalf;
        const float* wp = W + ((size_t)r * JD + nt * 16 + row) * C_IN + cbase;
        float4 w4 = *(const float4*)wp;
        float part = acc[0]*w4.x + acc[1]*w4.y + acc[2]*w4.z + acc[3]*w4.w;
#pragma unroll
        for (int off = 1; off < 32; off <<= 1) part += __shfl_xor(part, off, 32);
        if ((l & 31) == 0) bnew[2 * mt + rhalf][nt] = part * (1.f / (float)B_BATCH);
    }
    __syncthreads();

    // --- softmax for this block's 4 routes -> ctab (and b_ij chain) ------
    if (t < 4) {
        float bj[N_CAPS], m = -1e30f;
#pragma unroll
        for (int j = 0; j < N_CAPS; j++) {
            float base = ACCUM ? b_ij[(r0 + t) * N_CAPS + j] : 0.f;
            bj[j] = base + bnew[t][j];
            m = fmaxf(m, bj[j]);
        }
        if (!ACCUM) {
#pragma unroll
            for (int j = 0; j < N_CAPS; j++) b_ij[(r0 + t) * N_CAPS + j] = bj[j];
        }
        float sum = 0.f;
#pragma unroll
        for (int j = 0; j < N_CAPS; j++) { bj[j] = expf(bj[j] - m); sum += bj[j]; }
        float inv = 1.f / sum;
#pragma unroll
        for (int j = 0; j < N_CAPS; j++) ctab[(r0 + t) * N_CAPS + j] = bj[j] * inv;
    }
}

// final: squash s2 -> out (verified R16 k_rs_final)
__global__ __launch_bounds__(320) void k_rs_final(
    const float* __restrict__ s, float* __restrict__ out) {
    int t = threadIdx.x;                      // 320 = 2 b x 160 jd
    int bloc = t / JD, jd = t % JD;
    int b = blockIdx.x * 2 + bloc;
    float acc = s[(size_t)b * JD + jd];
    float sq = acc * acc;                     // lane%16 == jd%16 -> width-16 xor
#pragma unroll
    for (int off = 1; off < 16; off <<= 1) sq += __shfl_xor(sq, off, 16);
    float scale = sq / ((1.f + sq) * sqrtf(sq));
    out[(size_t)b * JD + jd] = acc * scale;
}

extern "C" void kernel_launch(void* const* d_in, const int* in_sizes, int n_in,
                              void* d_out, int out_size, void* d_ws, size_t ws_size,
                              hipStream_t stream) {
    const float* x = (const float*)d_in[0];   // [128,1152,8]
    const float* W = (const float*)d_in[1];   // [1,1152,10,16,8]
    float* out = (float*)d_out;               // [128,10,16,1]
    char* ws = (char*)d_ws;

    float*          s0   = (float*)(ws + 0);
    float*          s1   = (float*)(ws + 81920);
    float*          s2   = (float*)(ws + 163840);
    float*          b_ij = (float*)(ws + 245760);
    float*          ctab = (float*)(ws + 291840);
    unsigned short* xT   = (unsigned short*)(ws + 337920);

    // d1: transpose x->xT (streams x to L3) + zero s0..s2 + warm W to L3
    k_prep0<<<444, 256, 0, stream>>>(x, W, xT, (f32x4*)ws);

    // d2: iter1 (c=0.1) -> s0 (atomic)
    k_iter<1><<<dim3(KSPLIT, NG, BH), 256, 0, stream>>>(x, W, nullptr, s0);

    // d3: va1 -> b_ij (store), ctab
    k_va<0><<<288, 256, 0, stream>>>(xT, s0, W, b_ij, ctab);

    // d4: iter2 -> s1 (atomic)
    k_iter<0><<<dim3(KSPLIT, NG, BH), 256, 0, stream>>>(x, W, ctab, s1);

    // d5: va2 -> ctab (b_ij + upd2)
    k_va<1><<<288, 256, 0, stream>>>(xT, s1, W, b_ij, ctab);

    // d6: iter3 -> s2 (atomic)
    k_iter<0><<<dim3(KSPLIT, NG, BH), 256, 0, stream>>>(x, W, ctab, s2);

    // d7: final squash
    k_rs_final<<<64, 320, 0, stream>>>(s2, out);
}